// Round 4
// baseline (1069.632 us; speedup 1.0000x reference)
//
#include <hip/hip_runtime.h>
#include <stdint.h>

#define N3i 25600
#define N4i 6400
#define N5i 1600
#define NNi 33600
#define ECi 260000
#define EHi 120000

typedef unsigned short u16;
typedef __bf16 bf16x8 __attribute__((ext_vector_type(8)));
typedef float f32x4 __attribute__((ext_vector_type(4)));

__device__ __forceinline__ float b2f(u16 u) {
    union { float f; uint32_t i; } v; v.i = ((uint32_t)u) << 16; return v.f;
}
__device__ __forceinline__ u16 f2b(float f) {
    union { float f; uint32_t i; } v; v.f = f;
    uint32_t x = v.i;
    uint32_t r = (x + 0x7FFFu + ((x >> 16) & 1u)) >> 16;  // RNE
    return (u16)r;
}

// ---------------- dtype detection: flag=1 if inputs are bf16, 0 if fp32 ----------------
__global__ void detect_kernel(const void* __restrict__ c3raw, int* __restrict__ flag) {
    if (blockIdx.x == 0 && threadIdx.x == 0) {
        const uint32_t* p = (const uint32_t*)c3raw;
        int vote = 0;
        for (int i = 0; i < 256; i++) {
            uint32_t w = p[i];
            uint32_t lo = w & 0xFFFFu;
            uint32_t e = (lo >> 7) & 0xFFu;
            if (lo == 0u || (e >= 100u && e <= 127u)) vote++;
        }
        flag[0] = (vote >= 192) ? 1 : 0;
    }
}

// ---------------- utility kernels ----------------
__global__ void zero_i32(int* p, int n) {
    int i = blockIdx.x * 256 + threadIdx.x;
    if (i < n) p[i] = 0;
}

__global__ void hist_kernel(const int* __restrict__ dst, int* __restrict__ cnt, int ne) {
    int i = blockIdx.x * 256 + threadIdx.x;
    if (i < ne) {
        int d = dst[i];
        if ((unsigned)d < (unsigned)NNi) atomicAdd(&cnt[d], 1);
    }
}

__global__ void scan_kernel(const int* __restrict__ cnt, int* __restrict__ rs,
                            int* __restrict__ cursor, float* __restrict__ invdeg, int n) {
    __shared__ int buf[1024];
    __shared__ int base;
    int t = threadIdx.x;
    if (t == 0) { base = 0; rs[0] = 0; }
    __syncthreads();
    for (int i0 = 0; i0 < n; i0 += 1024) {
        int i = i0 + t;
        int v = (i < n) ? cnt[i] : 0;
        buf[t] = v;
        __syncthreads();
        for (int d = 1; d < 1024; d <<= 1) {
            int add = (t >= d) ? buf[t - d] : 0;
            __syncthreads();
            buf[t] += add;
            __syncthreads();
        }
        int incl = buf[t];
        int b = base;
        if (i < n) {
            rs[i + 1] = b + incl;
            cursor[i] = b + incl - v;
            int dv = v < 1 ? 1 : v;
            invdeg[i] = 1.0f / (float)dv;
        }
        __syncthreads();
        if (t == 1023) base = b + incl;
        __syncthreads();
    }
}

__global__ void fill_csr(const int* __restrict__ src, const int* __restrict__ dst,
                         int* __restrict__ cursor, int* __restrict__ csr, int ne) {
    int i = blockIdx.x * 256 + threadIdx.x;
    if (i < ne) {
        int d = dst[i];
        if ((unsigned)d < (unsigned)NNi) {
            int p = atomicAdd(&cursor[d], 1);
            if ((unsigned)p < (unsigned)ne) csr[p] = src[i];
        }
    }
}

// 1D convert raw (bf16 or fp32 per flag) -> bf16
__global__ void cvt1d(const void* __restrict__ in, u16* __restrict__ out, int n,
                      const int* __restrict__ flag) {
    int i = blockIdx.x * 256 + threadIdx.x;
    if (i >= n) return;
    out[i] = flag[0] ? ((const u16*)in)[i] : f2b(((const float*)in)[i]);
}

// input transpose: per batch z, raw in[R][C] -> bf16 out[C][R]
__global__ void transpose_in(const void* __restrict__ in, u16* __restrict__ out, int R, int C,
                             const int* __restrict__ flag) {
    __shared__ u16 tile[32][33];
    int isb = flag[0];
    int c0 = blockIdx.x * 32, r0 = blockIdx.y * 32;
    size_t boff = (size_t)blockIdx.z * R * C;
    const u16* inb = (const u16*)in + boff;
    const float* inf_ = (const float*)in + boff;
    u16* outp = out + boff;
    int tx = threadIdx.x, ty = threadIdx.y;   // block (32,8)
#pragma unroll
    for (int i = 0; i < 4; i++) {
        int r = r0 + ty + i * 8, c = c0 + tx;
        if (r < R && c < C) {
            size_t idx = (size_t)r * C + c;
            tile[ty + i * 8][tx] = isb ? inb[idx] : f2b(inf_[idx]);
        }
    }
    __syncthreads();
#pragma unroll
    for (int i = 0; i < 4; i++) {
        int c = c0 + ty + i * 8, r = r0 + tx;
        if (c < C && r < R) outp[(size_t)c * R + r] = tile[tx][ty + i * 8];
    }
}

// output transpose: per batch z, bf16 in[R][C] -> out[C][R] (store bf16 or fp32 per flag)
__global__ void transpose_out(const u16* __restrict__ in, void* __restrict__ outv,
                              size_t out_off, int R, int C, const int* __restrict__ flag) {
    __shared__ u16 tile[32][33];
    int isb = flag[0];
    int c0 = blockIdx.x * 32, r0 = blockIdx.y * 32;
    size_t boff = (size_t)blockIdx.z * R * C;
    const u16* inp = in + boff;
    int tx = threadIdx.x, ty = threadIdx.y;
#pragma unroll
    for (int i = 0; i < 4; i++) {
        int r = r0 + ty + i * 8, c = c0 + tx;
        if (r < R && c < C) tile[ty + i * 8][tx] = inp[(size_t)r * C + c];
    }
    __syncthreads();
#pragma unroll
    for (int i = 0; i < 4; i++) {
        int c = c0 + ty + i * 8, r = r0 + tx;
        if (c < C && r < R) {
            size_t o = out_off + boff + (size_t)c * R + r;
            u16 v = tile[tx][ty + i * 8];
            if (isb) ((u16*)outv)[o] = v;
            else ((float*)outv)[o] = b2f(v);
        }
    }
}

// conv weight transform: wt[n][tap*256+ci] = w[n][ci*9+tap]
__global__ void convw_kernel(const void* __restrict__ w, u16* __restrict__ wt,
                             const int* __restrict__ flag) {
    int i = blockIdx.x * 256 + threadIdx.x;
    if (i >= 256 * 2304) return;
    int n = i / 2304;
    int k = i - n * 2304;
    int tap = k >> 8, ci = k & 255;
    int si = n * 2304 + ci * 9 + tap;
    wt[i] = flag[0] ? ((const u16*)w)[si] : f2b(((const float*)w)[si]);
}

// ---------------- GNN gather: T = bf16(H + segsum(H[src]) * invdeg) ----------------
__global__ __launch_bounds__(256) void gather_kernel(
    const u16* __restrict__ H, const int* __restrict__ csr, const int* __restrict__ rs,
    const float* __restrict__ invdeg, u16* __restrict__ T, int ecap) {
    int node = blockIdx.x * 4 + (threadIdx.x >> 6);
    if (node >= NNi) return;
    int lane = threadIdx.x & 63;
    int c = lane * 4;
    int e0 = rs[node], e1 = rs[node + 1];
    e0 = e0 < 0 ? 0 : e0;
    e1 = e1 > ecap ? ecap : e1;
    float s0 = 0.f, s1 = 0.f, s2 = 0.f, s3 = 0.f;
    for (int e = e0; e < e1; e++) {
        int src = csr[e];
        src = ((unsigned)src < (unsigned)NNi) ? src : 0;
        ushort4 hv = *(const ushort4*)(H + (size_t)src * 256 + c);
        s0 += b2f(hv.x); s1 += b2f(hv.y); s2 += b2f(hv.z); s3 += b2f(hv.w);
    }
    float inv = invdeg[node];
    ushort4 hv = *(const ushort4*)(H + (size_t)node * 256 + c);
    ushort4 o;
    o.x = f2b(b2f(hv.x) + s0 * inv);
    o.y = f2b(b2f(hv.y) + s1 * inv);
    o.z = f2b(b2f(hv.z) + s2 * inv);
    o.w = f2b(b2f(hv.w) + s3 * inv);
    *(ushort4*)(T + (size_t)node * 256 + c) = o;
}

// ---------------- MFMA GEMM: C[M,256] = A[M,K] @ Bt[256,K]^T + bias, opt relu ----------------
// Staging: 128 rows x 32 k-elements per slab; 2 threads/row, each thread covers 16 u16
// = 32 bytes = TWO uint4 chunks (seg and seg+8). [Round-4 fix: previously only one uint4
// was written -> LDS holes -> uninitialized garbage into MFMA -> NaN/inf contagion.]
template <bool CONV, bool RELU>
__global__ __launch_bounds__(256) void gemm_kernel(
    const u16* __restrict__ A, int lda,
    const u16* __restrict__ Bt, int ldb,
    const u16* __restrict__ bias,
    u16* __restrict__ out, u16* __restrict__ out2,
    int M, int K, int H, int W) {
    __shared__ __align__(16) u16 As[128][40];
    __shared__ __align__(16) u16 Bs[128][40];
    int m0 = blockIdx.y * 128;
    int n0 = blockIdx.x * 128;
    int t = threadIdx.x;
    int wave = t >> 6, lane = t & 63;
    int wm = wave & 1, wn = wave >> 1;
    f32x4 acc[4][4] = {};

    int r = t >> 1;
    int seg = (t & 1) * 16;

    int arow = m0 + r;
    bool arow_ok = arow < M;
    int y_ = 0, x_ = 0;
    const u16* aptr = A + (size_t)arow * lda + seg;
    if (CONV) {
        if (arow_ok) {
            int HW = H * W;
            int b = arow / HW;
            int rem = arow - b * HW;
            y_ = rem / W;
            x_ = rem - y_ * W;
        }
    }
    const u16* bptr = Bt + (size_t)(n0 + r) * ldb + seg;

    for (int k0 = 0; k0 < K; k0 += 32) {
        uint4 av0 = make_uint4(0, 0, 0, 0), av1 = make_uint4(0, 0, 0, 0);
        if (!CONV) {
            if (arow_ok) {
                av0 = *(const uint4*)(aptr + k0);
                av1 = *(const uint4*)(aptr + k0 + 8);
            }
        } else {
            int tap = k0 >> 8;
            int dy = tap / 3 - 1;
            int dx = tap - (tap / 3) * 3 - 1;
            int yy = y_ + dy, xx = x_ + dx;
            if (arow_ok && (unsigned)yy < (unsigned)H && (unsigned)xx < (unsigned)W) {
                const u16* p = A + (size_t)(arow + dy * W + dx) * lda + (k0 & 255) + seg;
                av0 = *(const uint4*)p;
                av1 = *(const uint4*)(p + 8);
            }
        }
        uint4 bv0 = *(const uint4*)(bptr + k0);
        uint4 bv1 = *(const uint4*)(bptr + k0 + 8);
        __syncthreads();
        *(uint4*)&As[r][seg] = av0;
        *(uint4*)&As[r][seg + 8] = av1;
        *(uint4*)&Bs[r][seg] = bv0;
        *(uint4*)&Bs[r][seg + 8] = bv1;
        __syncthreads();

        int fm = lane & 15;
        int kq = (lane >> 4) * 8;
        bf16x8 af[4], bfv[4];
#pragma unroll
        for (int i = 0; i < 4; i++) af[i] = *(const bf16x8*)&As[wm * 64 + i * 16 + fm][kq];
#pragma unroll
        for (int j = 0; j < 4; j++) bfv[j] = *(const bf16x8*)&Bs[wn * 64 + j * 16 + fm][kq];
#pragma unroll
        for (int i = 0; i < 4; i++)
#pragma unroll
            for (int j = 0; j < 4; j++)
                acc[i][j] = __builtin_amdgcn_mfma_f32_16x16x32_bf16(af[i], bfv[j], acc[i][j], 0, 0, 0);
    }

    int q = lane >> 4, nl = lane & 15;
#pragma unroll
    for (int j = 0; j < 4; j++) {
        int n = n0 + wn * 64 + j * 16 + nl;
        float bv = b2f(bias[n]);
#pragma unroll
        for (int i = 0; i < 4; i++) {
            int mbase = m0 + wm * 64 + i * 16 + q * 4;
#pragma unroll
            for (int rg = 0; rg < 4; rg++) {
                int m = mbase + rg;
                if (m < M) {
                    float v = acc[i][j][rg] + bv;
                    if (RELU) v = fmaxf(v, 0.f);
                    u16 bs = f2b(v);
                    out[(size_t)m * 256 + n] = bs;
                    if (out2) out2[(size_t)m * 256 + n] = bs;
                }
            }
        }
    }
}

// ---------------- pyramid composition, in-place on P (order: q5, q4, q3) ----------------
__global__ void q5_kernel(u16* __restrict__ P, const u16* __restrict__ Hf) {
    int i = blockIdx.x * 256 + threadIdx.x;
    if (i >= N5i * 256) return;
    size_t idx = (size_t)(N3i + N4i) * 256 + i;
    P[idx] = f2b(b2f(P[idx]) + b2f(Hf[idx]));
}
__global__ void q4_kernel(u16* __restrict__ P, const u16* __restrict__ Hf) {
    int i = blockIdx.x * 256 + threadIdx.x;
    if (i >= N4i * 256) return;
    int node = i >> 8, c = i & 255;
    int b = node / 1600;
    int rem = node - b * 1600;
    int y = rem / 40, x = rem - (rem / 40) * 40;
    size_t idx = (size_t)(N3i + node) * 256 + c;
    size_t s5 = ((size_t)(N3i + N4i) + b * 400 + (y >> 1) * 20 + (x >> 1)) * 256 + c;
    P[idx] = f2b(b2f(P[idx]) + b2f(Hf[idx]) + b2f(P[s5]));
}
__global__ void q3_kernel(u16* __restrict__ P, const u16* __restrict__ Hf) {
    int i = blockIdx.x * 256 + threadIdx.x;
    if (i >= N3i * 256) return;
    int node = i >> 8, c = i & 255;
    int b = node / 6400;
    int rem = node - b * 6400;
    int y = rem / 80, x = rem - (rem / 80) * 80;
    size_t idx = (size_t)node * 256 + c;
    size_t s4 = ((size_t)N3i + b * 1600 + (y >> 1) * 40 + (x >> 1)) * 256 + c;
    P[idx] = f2b(b2f(P[idx]) + b2f(Hf[idx]) + b2f(P[s4]));
}

// ---------------- host ----------------
extern "C" void kernel_launch(void* const* d_in, const int* in_sizes, int n_in,
                              void* d_out, int out_size, void* d_ws, size_t ws_size,
                              hipStream_t stream) {
    (void)in_sizes; (void)n_in; (void)out_size; (void)ws_size;
    const void* c3 = d_in[0];
    const void* c4 = d_in[1];
    const void* c5 = d_in[2];
    const void* w3_1 = d_in[3];
    const void* b3_1 = d_in[4];
    const void* w4_1 = d_in[5];
    const void* b4_1 = d_in[6];
    const void* w5_1 = d_in[7];
    const void* b5_1 = d_in[8];
    const void* w3_3 = d_in[9];
    const void* b3_3 = d_in[10];
    const void* w4_3 = d_in[11];
    const void* b4_3 = d_in[12];
    const void* w5_3 = d_in[13];
    const void* b5_3 = d_in[14];
    const void* Wc = d_in[15];
    const void* bc = d_in[16];
    const void* Wh = d_in[17];
    const void* bh = d_in[18];
    const int* src_c = (const int*)d_in[19];
    const int* dst_c = (const int*)d_in[20];
    const int* src_h = (const int*)d_in[21];
    const int* dst_h = (const int*)d_in[22];

    char* w = (char*)d_ws;
    auto alloc = [&](size_t bytes) -> void* {
        void* p = (void*)w;
        w += (bytes + 255) & ~(size_t)255;
        return p;
    };
    // XT region: holds Xt3/Xt4/Xt5 (21.3 MB); after laterals it hosts T (17.2 MB) + WtC (3.54 MB)
    u16* XT  = (u16*)alloc(((size_t)N3i * 256 + (size_t)N4i * 512 + (size_t)N5i * 512) * 2);
    u16* Xt3 = XT;
    u16* Xt4 = XT + (size_t)N3i * 256;
    u16* Xt5 = Xt4 + (size_t)N4i * 512;
    u16* T   = XT;                          // alias (17,203,200 B <= 21,299,200 B region)
    u16* WtC = XT + (size_t)NNi * 256;      // alias, starts right after T (3.54 MB fits)
    u16* WtG = (u16*)alloc((size_t)9 * 65536 * 2);
    u16* W1  = (u16*)alloc((size_t)(65536 + 131072 + 131072) * 2);
    u16* BB  = (u16*)alloc((size_t)3840 * 2);   // biases: 3 lat | 6 bc | 3 bh | 3 conv
    u16* P   = (u16*)alloc((size_t)NNi * 256 * 2);
    u16* Ha  = (u16*)alloc((size_t)NNi * 256 * 2);
    u16* Hb  = (u16*)d_out;                 // alias d_out as scratch (>=17.2 MB either dtype)
    int* csr_c = (int*)alloc((size_t)ECi * 4);
    int* csr_h = (int*)alloc((size_t)EHi * 4);
    int* cnt2  = (int*)alloc((size_t)2 * NNi * 4);
    int* cnt_c = cnt2;
    int* cnt_h = cnt2 + NNi;
    int* rs_c  = (int*)alloc((size_t)(NNi + 1) * 4);
    int* rs_h  = (int*)alloc((size_t)(NNi + 1) * 4);
    int* cur_c = (int*)alloc((size_t)NNi * 4);
    int* cur_h = (int*)alloc((size_t)NNi * 4);
    float* inv_c = (float*)alloc((size_t)NNi * 4);
    float* inv_h = (float*)alloc((size_t)NNi * 4);
    int* flag  = (int*)alloc(256);

    // ---- dtype detection ----
    detect_kernel<<<1, 64, 0, stream>>>(c3, flag);

    // ---- CSR build (dtype-independent) ----
    zero_i32<<<(2 * NNi + 255) / 256, 256, 0, stream>>>(cnt2, 2 * NNi);
    hist_kernel<<<(ECi + 255) / 256, 256, 0, stream>>>(dst_c, cnt_c, ECi);
    hist_kernel<<<(EHi + 255) / 256, 256, 0, stream>>>(dst_h, cnt_h, EHi);
    scan_kernel<<<1, 1024, 0, stream>>>(cnt_c, rs_c, cur_c, inv_c, NNi);
    scan_kernel<<<1, 1024, 0, stream>>>(cnt_h, rs_h, cur_h, inv_h, NNi);
    fill_csr<<<(ECi + 255) / 256, 256, 0, stream>>>(src_c, dst_c, cur_c, csr_c, ECi);
    fill_csr<<<(EHi + 255) / 256, 256, 0, stream>>>(src_h, dst_h, cur_h, csr_h, EHi);

    // ---- convert small tensors (1x1 weights are [n][k] already; biases) ----
    cvt1d<<<256, 256, 0, stream>>>(w3_1, W1, 65536, flag);
    cvt1d<<<512, 256, 0, stream>>>(w4_1, W1 + 65536, 131072, flag);
    cvt1d<<<512, 256, 0, stream>>>(w5_1, W1 + 196608, 131072, flag);
    cvt1d<<<1, 256, 0, stream>>>(b3_1, BB + 0, 256, flag);
    cvt1d<<<1, 256, 0, stream>>>(b4_1, BB + 256, 256, flag);
    cvt1d<<<1, 256, 0, stream>>>(b5_1, BB + 512, 256, flag);
    cvt1d<<<6, 256, 0, stream>>>(bc, BB + 768, 1536, flag);
    cvt1d<<<3, 256, 0, stream>>>(bh, BB + 2304, 768, flag);
    cvt1d<<<1, 256, 0, stream>>>(b3_3, BB + 3072, 256, flag);
    cvt1d<<<1, 256, 0, stream>>>(b4_3, BB + 3328, 256, flag);
    cvt1d<<<1, 256, 0, stream>>>(b5_3, BB + 3584, 256, flag);

    // ---- input transposes (NCHW -> node-major), GNN weight transposes [k][n]->[n][k] ----
    transpose_in<<<dim3(200, 8, 4), dim3(32, 8), 0, stream>>>(c3, Xt3, 256, 6400, flag);
    transpose_in<<<dim3(50, 16, 4), dim3(32, 8), 0, stream>>>(c4, Xt4, 512, 1600, flag);
    transpose_in<<<dim3(13, 16, 4), dim3(32, 8), 0, stream>>>(c5, Xt5, 512, 400, flag);
    transpose_in<<<dim3(8, 8, 6), dim3(32, 8), 0, stream>>>(Wc, WtG, 256, 256, flag);
    transpose_in<<<dim3(8, 8, 3), dim3(32, 8), 0, stream>>>(Wh, WtG + (size_t)6 * 65536, 256, 256, flag);

    // ---- lateral 1x1 convs -> P (and H0 = Ha) ----
    gemm_kernel<false, false><<<dim3(2, 200), 256, 0, stream>>>(
        Xt3, 256, W1, 256, BB + 0, P, Ha, N3i, 256, 0, 0);
    gemm_kernel<false, false><<<dim3(2, 50), 256, 0, stream>>>(
        Xt4, 512, W1 + 65536, 512, BB + 256, P + (size_t)N3i * 256, Ha + (size_t)N3i * 256, N4i, 512, 0, 0);
    gemm_kernel<false, false><<<dim3(2, 13), 256, 0, stream>>>(
        Xt5, 512, W1 + 196608, 512, BB + 512, P + (size_t)(N3i + N4i) * 256, Ha + (size_t)(N3i + N4i) * 256, N5i, 512, 0, 0);

    // ---- conv weights AFTER laterals (WtC aliases Xt4/Xt5 tail) ----
    convw_kernel<<<2304, 256, 0, stream>>>(w3_3, WtC, flag);
    convw_kernel<<<2304, 256, 0, stream>>>(w4_3, WtC + (size_t)256 * 2304, flag);
    convw_kernel<<<2304, 256, 0, stream>>>(w5_3, WtC + (size_t)2 * 256 * 2304, flag);

    // ---- 9 GNN layers (T aliases XT[0..17.2MB], untouched by WtC) ----
    u16* Hcur = Ha;
    u16* Hnxt = Hb;
    for (int l = 0; l < 9; l++) {
        bool ctx = (l < 3) || (l >= 6);
        const int* csr = ctx ? csr_c : csr_h;
        const int* rs = ctx ? rs_c : rs_h;
        const float* inv = ctx ? inv_c : inv_h;
        int ecap = ctx ? ECi : EHi;
        int wi = (l < 3) ? l : (l < 6 ? 6 + (l - 3) : l - 3);
        const u16* bias = (l < 3) ? BB + 768 + l * 256
                        : (l < 6 ? BB + 2304 + (l - 3) * 256 : BB + 768 + (l - 3) * 256);
        gather_kernel<<<(NNi + 3) / 4, 256, 0, stream>>>(Hcur, csr, rs, inv, T, ecap);
        gemm_kernel<false, true><<<dim3(2, 263), 256, 0, stream>>>(
            T, 256, WtG + (size_t)wi * 65536, 256, bias, Hnxt, nullptr, NNi, 256, 0, 0);
        u16* tmp = Hcur; Hcur = Hnxt; Hnxt = tmp;
    }
    // after 9 swaps: Hcur = Hb (= d_out scratch), Hnxt = Ha -> reuse Ha for conv output
    u16* OutT = Hnxt;

    // ---- pyramid composition, in-place on P (reads Hcur before d_out is rewritten) ----
    q5_kernel<<<(N5i * 256 + 255) / 256, 256, 0, stream>>>(P, Hcur);
    q4_kernel<<<(N4i * 256 + 255) / 256, 256, 0, stream>>>(P, Hcur);
    q3_kernel<<<(N3i * 256 + 255) / 256, 256, 0, stream>>>(P, Hcur);

    // ---- 3x3 convs (9-tap gathered GEMM) ----
    gemm_kernel<true, false><<<dim3(2, 200), 256, 0, stream>>>(
        P, 256, WtC, 2304, BB + 3072, OutT, nullptr, N3i, 2304, 80, 80);
    gemm_kernel<true, false><<<dim3(2, 50), 256, 0, stream>>>(
        P + (size_t)N3i * 256, 256, WtC + (size_t)256 * 2304, 2304, BB + 3328,
        OutT + (size_t)N3i * 256, nullptr, N4i, 2304, 40, 40);
    gemm_kernel<true, false><<<dim3(2, 13), 256, 0, stream>>>(
        P + (size_t)(N3i + N4i) * 256, 256, WtC + (size_t)2 * 256 * 2304, 2304, BB + 3584,
        OutT + (size_t)(N3i + N4i) * 256, nullptr, N5i, 2304, 20, 20);

    // ---- node-major -> NCHW output (store bf16 or fp32 per flag) ----
    transpose_out<<<dim3(8, 200, 4), dim3(32, 8), 0, stream>>>(OutT, d_out, 0, 6400, 256, flag);
    transpose_out<<<dim3(8, 50, 4), dim3(32, 8), 0, stream>>>(
        OutT + (size_t)N3i * 256, d_out, (size_t)4 * 256 * 6400, 1600, 256, flag);
    transpose_out<<<dim3(8, 13, 4), dim3(32, 8), 0, stream>>>(
        OutT + (size_t)(N3i + N4i) * 256, d_out, (size_t)4 * 256 * (6400 + 1600), 400, 256, flag);
}